// Round 17
// baseline (46.564 us; speedup 1.0000x reference)
//
#include <hip/hip_runtime.h>
#include <hip/hip_bf16.h>
#include <hip/hip_fp16.h>

// Problem constants (fixed by setup_inputs)
#define CIN      8
#define HH       100
#define WW       152
#define HWSZ     (HH * WW)          // 15200
#define OHGT     200
#define OWID     304
#define PPI      419                 // params per instance: 169 body + 169 edge + 81 fused
#define OUT_PER_INST (OHGT * OWID)   // 60800

#define RSTRIP   10                  // interior logit rows per block (100 = 10*10)
#define TROWS    11                  // 10 interior + 1 halo
#define NSTRIPS  10
#define NQUAD    (TROWS * 38)        // 418 quads of 4 px per block
#define CH_ITEMS (3 * 5 * 76)        // 1140 upsample items per 5-row chunk

// Per-instance param layout (row of 419 floats):
//  body:  w1[8][10]@0  w2[8][8]@80  w3[8]@144  b1[8]@152 b2[8]@160 b3@168
//  edge:  same +169
//  fused: wf1[8][8]@338 wf2[8]@402 bf1[8]@410 bf2@418

typedef float vf4 __attribute__((ext_vector_type(4)));

// R8-proven: vector w*x+a (fuses+packs). R9: scalarized fmaf WORSE.
// R13: LDS-staged weights WORSE. R15: interleaved dual-quad spills --
// quads must be SEQUENTIAL (R16). R17: chunked ph1/ph2 pipeline so the
// store drain overlaps pass-B compute; regular (L2-buffered) stores.
__device__ __forceinline__ vf4 fma4(float w, vf4 x, vf4 a) { return w * x + a; }
__device__ __forceinline__ vf4 relu4(vf4 x) {
    vf4 r; r.x = fmaxf(x.x, 0.f); r.y = fmaxf(x.y, 0.f);
    r.z = fmaxf(x.z, 0.f); r.w = fmaxf(x.w, 0.f); return r;
}

// ------------------------------------------------------------------------
// Fused kernel, 256 threads. Block = (instance n, 10-row strip s).
// Pipeline: passA(quads 0..255) | bar | ph2(rows 0..4) [stores drain under
// passB] | passB(quads 256..417, writes tile rows >=6 only -- disjoint from
// ph2a's reads of rows <=5, no barrier needed] | bar | ph2(rows 5..9).
// ------------------------------------------------------------------------
__global__ __launch_bounds__(256) void dmh_fused9_kernel(
    const float* __restrict__ fbody,      // [2][8][H][W]
    const float* __restrict__ fedge,      // [2][8][H][W]
    const float* __restrict__ params,     // [n_inst][419]
    const float* __restrict__ locs,       // [n_inst][2]
    const float* __restrict__ soi_tab,    // [5]
    const int*   __restrict__ im_inds,    // [n_inst]
    const int*   __restrict__ fpn_levels, // [n_inst]
    float* __restrict__ out,              // [3][n_inst][200][304]
    int n_inst)
{
    const int s   = blockIdx.x;
    const int n   = blockIdx.y;
    const int tid = threadIdx.x;
    const int r0  = RSTRIP * s;

    __shared__ float slog[3][TROWS][WW];  // 20.1 KB

    const float* __restrict__ p = params + (size_t)n * PPI;
    const int   im      = im_inds[n];
    const float inv_soi = 1.0f / soi_tab[fpn_levels[n]];
    const float sx = (locs[2 * n]     - 4.0f) * inv_soi;
    const float sy = (locs[2 * n + 1] - 4.0f) * inv_soi;
    const float k8 = 8.0f * inv_soi;

    const float* __restrict__ fb_base = fbody + (size_t)im * CIN * HWSZ;
    const float* __restrict__ fe_base = fedge + (size_t)im * CIN * HWSZ;

    // ---- one 4-px quad of the dynamic MLPs -> LDS (R11 body, verbatim) ----
    auto do_quad = [&](int quad) {
        const int rl = quad / 38;
        const int c  = (quad - rl * 38) * 4;  // 0,4,...,148
        const int r  = min(r0 + rl, HH - 1);  // halo row clamps (edge-pad)
        const int px = r * WW + c;

        const float dx0 = sx - (float)c * k8;
        const vf4 dx = { dx0, dx0 - k8, dx0 - 2.f * k8, dx0 - 3.f * k8 };
        const float dyv = sy - (float)r * k8;
        const vf4 dy = { dyv, dyv, dyv, dyv };

        const float* __restrict__ fb = fb_base + px;
        const float* __restrict__ fe = fe_base + px;

        vf4 inb[10], ine[8];
        inb[0] = dx; inb[1] = dy;
        #pragma unroll
        for (int k = 0; k < 8; ++k)
            inb[k + 2] = *(const vf4*)(fb + k * HWSZ);   // 16B coalesced
        #pragma unroll
        for (int k = 0; k < 8; ++k)
            ine[k] = *(const vf4*)(fe + k * HWSZ);

        vf4 h1[8];

        // body head
        #pragma unroll
        for (int o = 0; o < 8; ++o) {
            vf4 a = p[152 + o];
            #pragma unroll
            for (int k = 0; k < 10; ++k) a = fma4(p[o * 10 + k], inb[k], a);
            h1[o] = relu4(a);
        }
        vf4 h2b[8];                       // later becomes hs = h2b + h2e
        #pragma unroll
        for (int o = 0; o < 8; ++o) {
            vf4 a = p[160 + o];
            #pragma unroll
            for (int k = 0; k < 8; ++k) a = fma4(p[80 + o * 8 + k], h1[k], a);
            h2b[o] = relu4(a);
        }
        vf4 lb = p[168];
        #pragma unroll
        for (int k = 0; k < 8; ++k) lb = fma4(p[144 + k], h2b[k], lb);

        // edge head (h1 regs reused; h2e never materialized as array)
        #pragma unroll
        for (int o = 0; o < 8; ++o) {
            vf4 a = p[169 + 152 + o];
            a = fma4(p[169 + o * 10 + 0], dx, a);
            a = fma4(p[169 + o * 10 + 1], dy, a);
            #pragma unroll
            for (int k = 0; k < 8; ++k) a = fma4(p[169 + o * 10 + 2 + k], ine[k], a);
            h1[o] = relu4(a);
        }
        vf4 le = p[169 + 168];
        #pragma unroll
        for (int o = 0; o < 8; ++o) {
            vf4 a = p[169 + 160 + o];
            #pragma unroll
            for (int k = 0; k < 8; ++k) a = fma4(p[169 + 80 + o * 8 + k], h1[k], a);
            const vf4 he = relu4(a);
            le = fma4(p[169 + 144 + o], he, le);   // incremental edge logit
            h2b[o] = h2b[o] + he;                  // hs in place
        }

        // fused head on hs
        vf4 hf[8];
        #pragma unroll
        for (int o = 0; o < 8; ++o) {
            vf4 a = p[410 + o];
            #pragma unroll
            for (int k = 0; k < 8; ++k) a = fma4(p[338 + o * 8 + k], h2b[k], a);
            hf[o] = relu4(a);
        }
        vf4 lf = p[418];
        #pragma unroll
        for (int k = 0; k < 8; ++k) lf = fma4(p[402 + k], hf[k], lf);

        *(vf4*)&slog[0][rl][c] = lb;   // 16B-aligned LDS writes (c%4==0)
        *(vf4*)&slog[1][rl][c] = le;
        *(vf4*)&slog[2][rl][c] = lf;
    };

    // ---- ph2 for a 5-row chunk: x2 aligned_bilinear + sigmoid + fp32 stores ----
    // rowbase = first interior row of the chunk (0 or 5). Reads tile rows
    // [rowbase, rowbase+5]. Closed form as proven in R10:
    //   x=4q: (L[2q-1]+L[2q])/2  x=4q+1: L[2q]
    //   x=4q+2: (L[2q]+L[2q+1])/2  x=4q+3: L[2q+1]  (cols clamped)
    //   row A: y=2r+1; row B: y=2r+2 (avg rows rr,rr+1); y=0==y=1; drop y=200.
    auto do_ph2 = [&](int rowbase) {
        for (int it = tid; it < CH_ITEMS; it += 256) {
            const int h   = it / (5 * 76);
            const int rem = it - h * (5 * 76);
            const int rr  = rowbase + rem / 76;
            const int q   = rem - (rem / 76) * 76;
            const int r   = r0 + rr;

            const int cm = max(2 * q - 1, 0);
            const int c0 = 2 * q;
            const int cp = min(2 * q + 1, WW - 1);

            const float Lm0 = slog[h][rr][cm],     L00 = slog[h][rr][c0],     Lp0 = slog[h][rr][cp];
            const float Lm1 = slog[h][rr + 1][cm], L01 = slog[h][rr + 1][c0], Lp1 = slog[h][rr + 1][cp];

            const float a0 = 0.5f * (Lm0 + L00);
            const float a1 = L00;
            const float a2 = 0.5f * (L00 + Lp0);
            const float a3 = Lp0;
            const float m  = 0.5f * (Lm0 + Lm1);
            const float z  = 0.5f * (L00 + L01);
            const float pz = 0.5f * (Lp0 + Lp1);
            const float b0 = 0.5f * (m + z);
            const float b1 = z;
            const float b2 = 0.5f * (z + pz);
            const float b3 = pz;

            vf4 A, B;
            A.x = 1.0f / (1.0f + __expf(-a0));
            A.y = 1.0f / (1.0f + __expf(-a1));
            A.z = 1.0f / (1.0f + __expf(-a2));
            A.w = 1.0f / (1.0f + __expf(-a3));
            B.x = 1.0f / (1.0f + __expf(-b0));
            B.y = 1.0f / (1.0f + __expf(-b1));
            B.z = 1.0f / (1.0f + __expf(-b2));
            B.w = 1.0f / (1.0f + __expf(-b3));

            float* __restrict__ O = out + ((size_t)h * n_inst + n) * OUT_PER_INST;
            const int xq = 4 * q;
            *(vf4*)(O + (size_t)(2 * r + 1) * OWID + xq) = A;          // y = 2r+1
            if (r == 0)
                *(vf4*)(O + xq) = A;                                    // y = 0 (== y=1)
            if (r < HH - 1)
                *(vf4*)(O + (size_t)(2 * r + 2) * OWID + xq) = B;      // y = 2r+2
        }
    };

    // ---------------- Pipelined phases ----------------
    do_quad(tid);                    // pass A: quads 0..255 (tile rows 0..6 partial)
    __syncthreads();                 // rows 0..5 now complete
    do_ph2(0);                       // stores for rows 0..4 -> drain under pass B
    if (tid < NQUAD - 256)           // pass B: quads 256..417 (writes rows >= 6 only;
        do_quad(256 + tid);          //  disjoint from ph2a's reads of rows <= 5)
    __syncthreads();                 // full tile complete
    do_ph2(5);                       // stores for rows 5..9
}

extern "C" void kernel_launch(void* const* d_in, const int* in_sizes, int n_in,
                              void* d_out, int out_size, void* d_ws, size_t ws_size,
                              hipStream_t stream) {
    const float* fbody   = (const float*)d_in[0];
    const float* fedge   = (const float*)d_in[1];
    const float* params  = (const float*)d_in[2];
    const float* locs    = (const float*)d_in[3];
    const float* soi     = (const float*)d_in[4];
    const int*   im_inds = (const int*)d_in[5];
    const int*   fpn     = (const int*)d_in[6];
    // d_in[7] = mask_feat_stride (always 8; factor=2 baked into the closed form)

    const int n_inst = in_sizes[5];  // 128

    dim3 grid(NSTRIPS, n_inst);
    dmh_fused9_kernel<<<grid, dim3(256), 0, stream>>>(
        fbody, fedge, params, locs, soi, im_inds, fpn,
        (float*)d_out, n_inst);
}

// Round 18
// 46.276 us; speedup vs baseline: 1.0062x; 1.0062x over previous
//
#include <hip/hip_runtime.h>
#include <hip/hip_bf16.h>
#include <hip/hip_fp16.h>

// Problem constants (fixed by setup_inputs)
#define CIN      8
#define HH       100
#define WW       152
#define HWSZ     (HH * WW)          // 15200
#define OHGT     200
#define OWID     304
#define PPI      419                 // params per instance: 169 body + 169 edge + 81 fused
#define OUT_PER_INST (OHGT * OWID)   // 60800

#define RSTRIP   10                  // interior logit rows per block (100 = 10*10)
#define TROWS    11                  // 10 interior + 1 halo
#define NSTRIPS  10
#define NQUAD    (TROWS * 38)        // 418 quads of 4 px per block
#define CH_ITEMS (3 * 5 * 76)        // 1140 upsample items per 5-row chunk

// Per-instance param layout (row of 419 floats):
//  body:  w1[8][10]@0  w2[8][8]@80  w3[8]@144  b1[8]@152 b2[8]@160 b3@168
//  edge:  same +169
//  fused: wf1[8][8]@338 wf2[8]@402 bf1[8]@410 bf2@418

typedef float vf4 __attribute__((ext_vector_type(4)));

// R8-proven: vector w*x+a (fuses+packs). R9: scalarized fmaf WORSE.
// R13: LDS-staged weights WORSE. R15: interleaved dual-quad spills.
// R17: unfenced ph1/ph2 interleave -> scheduler hoisted pass-B loads across
// ph2a -> spill (VGPR=60, FETCH=9.6GB). R18: sched_barrier(0) fences at
// phase boundaries to pin phase-local live ranges.
__device__ __forceinline__ vf4 fma4(float w, vf4 x, vf4 a) { return w * x + a; }
__device__ __forceinline__ vf4 relu4(vf4 x) {
    vf4 r; r.x = fmaxf(x.x, 0.f); r.y = fmaxf(x.y, 0.f);
    r.z = fmaxf(x.z, 0.f); r.w = fmaxf(x.w, 0.f); return r;
}

// ------------------------------------------------------------------------
// Fused kernel, 256 threads. Block = (instance n, 10-row strip s).
// Pipeline: passA(quads 0..255) | bar | ph2(rows 0..4) [stores drain under
// passB] | passB(quads 256..417, writes tile rows >=6 only -- disjoint from
// ph2a's reads of rows <=5] | bar | ph2(rows 5..9).
// sched_barrier(0) at each phase boundary prevents cross-phase code motion.
// ------------------------------------------------------------------------
__global__ __launch_bounds__(256) void dmh_fused10_kernel(
    const float* __restrict__ fbody,      // [2][8][H][W]
    const float* __restrict__ fedge,      // [2][8][H][W]
    const float* __restrict__ params,     // [n_inst][419]
    const float* __restrict__ locs,       // [n_inst][2]
    const float* __restrict__ soi_tab,    // [5]
    const int*   __restrict__ im_inds,    // [n_inst]
    const int*   __restrict__ fpn_levels, // [n_inst]
    float* __restrict__ out,              // [3][n_inst][200][304]
    int n_inst)
{
    const int s   = blockIdx.x;
    const int n   = blockIdx.y;
    const int tid = threadIdx.x;
    const int r0  = RSTRIP * s;

    __shared__ float slog[3][TROWS][WW];  // 20.1 KB

    const float* __restrict__ p = params + (size_t)n * PPI;
    const int   im      = im_inds[n];
    const float inv_soi = 1.0f / soi_tab[fpn_levels[n]];
    const float sx = (locs[2 * n]     - 4.0f) * inv_soi;
    const float sy = (locs[2 * n + 1] - 4.0f) * inv_soi;
    const float k8 = 8.0f * inv_soi;

    const float* __restrict__ fb_base = fbody + (size_t)im * CIN * HWSZ;
    const float* __restrict__ fe_base = fedge + (size_t)im * CIN * HWSZ;

    // ---- one 4-px quad of the dynamic MLPs -> LDS (R11 body, verbatim) ----
    auto do_quad = [&](int quad) {
        const int rl = quad / 38;
        const int c  = (quad - rl * 38) * 4;  // 0,4,...,148
        const int r  = min(r0 + rl, HH - 1);  // halo row clamps (edge-pad)
        const int px = r * WW + c;

        const float dx0 = sx - (float)c * k8;
        const vf4 dx = { dx0, dx0 - k8, dx0 - 2.f * k8, dx0 - 3.f * k8 };
        const float dyv = sy - (float)r * k8;
        const vf4 dy = { dyv, dyv, dyv, dyv };

        const float* __restrict__ fb = fb_base + px;
        const float* __restrict__ fe = fe_base + px;

        vf4 inb[10], ine[8];
        inb[0] = dx; inb[1] = dy;
        #pragma unroll
        for (int k = 0; k < 8; ++k)
            inb[k + 2] = *(const vf4*)(fb + k * HWSZ);   // 16B coalesced
        #pragma unroll
        for (int k = 0; k < 8; ++k)
            ine[k] = *(const vf4*)(fe + k * HWSZ);

        vf4 h1[8];

        // body head
        #pragma unroll
        for (int o = 0; o < 8; ++o) {
            vf4 a = p[152 + o];
            #pragma unroll
            for (int k = 0; k < 10; ++k) a = fma4(p[o * 10 + k], inb[k], a);
            h1[o] = relu4(a);
        }
        vf4 h2b[8];                       // later becomes hs = h2b + h2e
        #pragma unroll
        for (int o = 0; o < 8; ++o) {
            vf4 a = p[160 + o];
            #pragma unroll
            for (int k = 0; k < 8; ++k) a = fma4(p[80 + o * 8 + k], h1[k], a);
            h2b[o] = relu4(a);
        }
        vf4 lb = p[168];
        #pragma unroll
        for (int k = 0; k < 8; ++k) lb = fma4(p[144 + k], h2b[k], lb);

        // edge head (h1 regs reused; h2e never materialized as array)
        #pragma unroll
        for (int o = 0; o < 8; ++o) {
            vf4 a = p[169 + 152 + o];
            a = fma4(p[169 + o * 10 + 0], dx, a);
            a = fma4(p[169 + o * 10 + 1], dy, a);
            #pragma unroll
            for (int k = 0; k < 8; ++k) a = fma4(p[169 + o * 10 + 2 + k], ine[k], a);
            h1[o] = relu4(a);
        }
        vf4 le = p[169 + 168];
        #pragma unroll
        for (int o = 0; o < 8; ++o) {
            vf4 a = p[169 + 160 + o];
            #pragma unroll
            for (int k = 0; k < 8; ++k) a = fma4(p[169 + 80 + o * 8 + k], h1[k], a);
            const vf4 he = relu4(a);
            le = fma4(p[169 + 144 + o], he, le);   // incremental edge logit
            h2b[o] = h2b[o] + he;                  // hs in place
        }

        // fused head on hs
        vf4 hf[8];
        #pragma unroll
        for (int o = 0; o < 8; ++o) {
            vf4 a = p[410 + o];
            #pragma unroll
            for (int k = 0; k < 8; ++k) a = fma4(p[338 + o * 8 + k], h2b[k], a);
            hf[o] = relu4(a);
        }
        vf4 lf = p[418];
        #pragma unroll
        for (int k = 0; k < 8; ++k) lf = fma4(p[402 + k], hf[k], lf);

        *(vf4*)&slog[0][rl][c] = lb;   // 16B-aligned LDS writes (c%4==0)
        *(vf4*)&slog[1][rl][c] = le;
        *(vf4*)&slog[2][rl][c] = lf;
    };

    // ---- ph2 for a 5-row chunk: x2 aligned_bilinear + sigmoid + fp32 stores ----
    // rowbase = first interior row of the chunk (0 or 5). Reads tile rows
    // [rowbase, rowbase+5]. Closed form as proven in R10:
    //   x=4q: (L[2q-1]+L[2q])/2  x=4q+1: L[2q]
    //   x=4q+2: (L[2q]+L[2q+1])/2  x=4q+3: L[2q+1]  (cols clamped)
    //   row A: y=2r+1; row B: y=2r+2 (avg rows rr,rr+1); y=0==y=1; drop y=200.
    auto do_ph2 = [&](int rowbase) {
        for (int it = tid; it < CH_ITEMS; it += 256) {
            const int h   = it / (5 * 76);
            const int rem = it - h * (5 * 76);
            const int rr  = rowbase + rem / 76;
            const int q   = rem - (rem / 76) * 76;
            const int r   = r0 + rr;

            const int cm = max(2 * q - 1, 0);
            const int c0 = 2 * q;
            const int cp = min(2 * q + 1, WW - 1);

            const float Lm0 = slog[h][rr][cm],     L00 = slog[h][rr][c0],     Lp0 = slog[h][rr][cp];
            const float Lm1 = slog[h][rr + 1][cm], L01 = slog[h][rr + 1][c0], Lp1 = slog[h][rr + 1][cp];

            const float a0 = 0.5f * (Lm0 + L00);
            const float a1 = L00;
            const float a2 = 0.5f * (L00 + Lp0);
            const float a3 = Lp0;
            const float m  = 0.5f * (Lm0 + Lm1);
            const float z  = 0.5f * (L00 + L01);
            const float pz = 0.5f * (Lp0 + Lp1);
            const float b0 = 0.5f * (m + z);
            const float b1 = z;
            const float b2 = 0.5f * (z + pz);
            const float b3 = pz;

            vf4 A, B;
            A.x = 1.0f / (1.0f + __expf(-a0));
            A.y = 1.0f / (1.0f + __expf(-a1));
            A.z = 1.0f / (1.0f + __expf(-a2));
            A.w = 1.0f / (1.0f + __expf(-a3));
            B.x = 1.0f / (1.0f + __expf(-b0));
            B.y = 1.0f / (1.0f + __expf(-b1));
            B.z = 1.0f / (1.0f + __expf(-b2));
            B.w = 1.0f / (1.0f + __expf(-b3));

            float* __restrict__ O = out + ((size_t)h * n_inst + n) * OUT_PER_INST;
            const int xq = 4 * q;
            *(vf4*)(O + (size_t)(2 * r + 1) * OWID + xq) = A;          // y = 2r+1
            if (r == 0)
                *(vf4*)(O + xq) = A;                                    // y = 0 (== y=1)
            if (r < HH - 1)
                *(vf4*)(O + (size_t)(2 * r + 2) * OWID + xq) = B;      // y = 2r+2
        }
    };

    // ---------------- Pipelined phases with code-motion fences ----------------
    do_quad(tid);                              // pass A: quads 0..255
    __syncthreads();                           // rows 0..5 complete
    __builtin_amdgcn_sched_barrier(0);         // fence: no ph2a code before this
    do_ph2(0);                                 // stores rows 0..4 (drain under pass B)
    __builtin_amdgcn_sched_barrier(0);         // fence: keep pass-B loads OUT of ph2a
    if (tid < NQUAD - 256)                     // pass B: quads 256..417 (rows >= 6)
        do_quad(256 + tid);
    __syncthreads();                           // full tile complete
    __builtin_amdgcn_sched_barrier(0);         // fence: no ph2b hoist into pass B
    do_ph2(5);                                 // stores rows 5..9
}

extern "C" void kernel_launch(void* const* d_in, const int* in_sizes, int n_in,
                              void* d_out, int out_size, void* d_ws, size_t ws_size,
                              hipStream_t stream) {
    const float* fbody   = (const float*)d_in[0];
    const float* fedge   = (const float*)d_in[1];
    const float* params  = (const float*)d_in[2];
    const float* locs    = (const float*)d_in[3];
    const float* soi     = (const float*)d_in[4];
    const int*   im_inds = (const int*)d_in[5];
    const int*   fpn     = (const int*)d_in[6];
    // d_in[7] = mask_feat_stride (always 8; factor=2 baked into the closed form)

    const int n_inst = in_sizes[5];  // 128

    dim3 grid(NSTRIPS, n_inst);
    dmh_fused10_kernel<<<grid, dim3(256), 0, stream>>>(
        fbody, fedge, params, locs, soi, im_inds, fpn,
        (float*)d_out, n_inst);
}

// Round 19
// 42.175 us; speedup vs baseline: 1.1041x; 1.0972x over previous
//
#include <hip/hip_runtime.h>
#include <hip/hip_bf16.h>
#include <hip/hip_fp16.h>

// Problem constants (fixed by setup_inputs)
#define CIN      8
#define HH       100
#define WW       152
#define HWSZ     (HH * WW)          // 15200
#define OHGT     200
#define OWID     304
#define PPI      419                 // params per instance: 169 body + 169 edge + 81 fused
#define OUT_PER_INST (OHGT * OWID)   // 60800

#define RSTRIP   10                  // interior logit rows per block (100 = 10*10)
#define TROWS    11                  // 10 interior + 1 halo
#define NSTRIPS  10
#define NQUAD    (TROWS * 38)        // 418 quads of 4 px per block
#define P2ITEMS  (3 * RSTRIP * 76)   // 2280 upsample items per block

// Per-instance param layout (row of 419 floats):
//  body:  w1[8][10]@0  w2[8][8]@80  w3[8]@144  b1[8]@152 b2[8]@160 b3@168
//  edge:  same +169
//  fused: wf1[8][8]@338 wf2[8]@402 bf1[8]@410 bf2@418

typedef float vf4 __attribute__((ext_vector_type(4)));

// FINAL (R19 = R16 revert, best measured 42.15 us). Session ledger:
//  R8: vector w*x+a (fuses+packs) -- scalarized fmaf is WORSE (R9).
//  R13: LDS-staged weights WORSE (SGPR weights are free FMA operands).
//  R15: interleaved dual-quad spills (VGPR=68, GBs of scratch fetch).
//  R16: sequential quad passes + barrier = register firewall. BEST.
//  R17/R18: intra-block ph1/ph2 pipelining regresses (spill unfenced;
//           no overlap fenced). R12: MFMA loses (staging >> weight savings).
__device__ __forceinline__ vf4 fma4(float w, vf4 x, vf4 a) { return w * x + a; }
__device__ __forceinline__ vf4 relu4(vf4 x) {
    vf4 r; r.x = fmaxf(x.x, 0.f); r.y = fmaxf(x.y, 0.f);
    r.z = fmaxf(x.z, 0.f); r.w = fmaxf(x.w, 0.f); return r;
}

// ------------------------------------------------------------------------
// Fused kernel, 256 threads. Block = (instance n, 10-row strip s).
// Phase 1: two SEQUENTIAL quad passes (A: 256 quads, B: 162 quads) with a
// barrier between to keep register pressure at single-quad level.
// Phase 2: closed-form x2 aligned_bilinear + sigmoid, NT vf4 stores.
// ------------------------------------------------------------------------
__global__ __launch_bounds__(256) void dmh_fused8_kernel(
    const float* __restrict__ fbody,      // [2][8][H][W]
    const float* __restrict__ fedge,      // [2][8][H][W]
    const float* __restrict__ params,     // [n_inst][419]
    const float* __restrict__ locs,       // [n_inst][2]
    const float* __restrict__ soi_tab,    // [5]
    const int*   __restrict__ im_inds,    // [n_inst]
    const int*   __restrict__ fpn_levels, // [n_inst]
    float* __restrict__ out,              // [3][n_inst][200][304]
    int n_inst)
{
    const int s   = blockIdx.x;
    const int n   = blockIdx.y;
    const int tid = threadIdx.x;
    const int r0  = RSTRIP * s;

    __shared__ float slog[3][TROWS][WW];  // 20.1 KB

    const float* __restrict__ p = params + (size_t)n * PPI;
    const int   im      = im_inds[n];
    const float inv_soi = 1.0f / soi_tab[fpn_levels[n]];
    const float sx = (locs[2 * n]     - 4.0f) * inv_soi;
    const float sy = (locs[2 * n + 1] - 4.0f) * inv_soi;
    const float k8 = 8.0f * inv_soi;

    const float* __restrict__ fb_base = fbody + (size_t)im * CIN * HWSZ;
    const float* __restrict__ fe_base = fedge + (size_t)im * CIN * HWSZ;

    // ---- one 4-px quad of the dynamic MLPs -> LDS (R11 body, verbatim) ----
    auto do_quad = [&](int quad) {
        const int rl = quad / 38;
        const int c  = (quad - rl * 38) * 4;  // 0,4,...,148
        const int r  = min(r0 + rl, HH - 1);  // halo row clamps (edge-pad)
        const int px = r * WW + c;

        const float dx0 = sx - (float)c * k8;
        const vf4 dx = { dx0, dx0 - k8, dx0 - 2.f * k8, dx0 - 3.f * k8 };
        const float dyv = sy - (float)r * k8;
        const vf4 dy = { dyv, dyv, dyv, dyv };

        const float* __restrict__ fb = fb_base + px;
        const float* __restrict__ fe = fe_base + px;

        vf4 inb[10], ine[8];
        inb[0] = dx; inb[1] = dy;
        #pragma unroll
        for (int k = 0; k < 8; ++k)
            inb[k + 2] = *(const vf4*)(fb + k * HWSZ);   // 16B coalesced
        #pragma unroll
        for (int k = 0; k < 8; ++k)
            ine[k] = *(const vf4*)(fe + k * HWSZ);

        vf4 h1[8];

        // body head
        #pragma unroll
        for (int o = 0; o < 8; ++o) {
            vf4 a = p[152 + o];
            #pragma unroll
            for (int k = 0; k < 10; ++k) a = fma4(p[o * 10 + k], inb[k], a);
            h1[o] = relu4(a);
        }
        vf4 h2b[8];                       // later becomes hs = h2b + h2e
        #pragma unroll
        for (int o = 0; o < 8; ++o) {
            vf4 a = p[160 + o];
            #pragma unroll
            for (int k = 0; k < 8; ++k) a = fma4(p[80 + o * 8 + k], h1[k], a);
            h2b[o] = relu4(a);
        }
        vf4 lb = p[168];
        #pragma unroll
        for (int k = 0; k < 8; ++k) lb = fma4(p[144 + k], h2b[k], lb);

        // edge head (h1 regs reused; h2e never materialized as array)
        #pragma unroll
        for (int o = 0; o < 8; ++o) {
            vf4 a = p[169 + 152 + o];
            a = fma4(p[169 + o * 10 + 0], dx, a);
            a = fma4(p[169 + o * 10 + 1], dy, a);
            #pragma unroll
            for (int k = 0; k < 8; ++k) a = fma4(p[169 + o * 10 + 2 + k], ine[k], a);
            h1[o] = relu4(a);
        }
        vf4 le = p[169 + 168];
        #pragma unroll
        for (int o = 0; o < 8; ++o) {
            vf4 a = p[169 + 160 + o];
            #pragma unroll
            for (int k = 0; k < 8; ++k) a = fma4(p[169 + 80 + o * 8 + k], h1[k], a);
            const vf4 he = relu4(a);
            le = fma4(p[169 + 144 + o], he, le);   // incremental edge logit
            h2b[o] = h2b[o] + he;                  // hs in place
        }

        // fused head on hs
        vf4 hf[8];
        #pragma unroll
        for (int o = 0; o < 8; ++o) {
            vf4 a = p[410 + o];
            #pragma unroll
            for (int k = 0; k < 8; ++k) a = fma4(p[338 + o * 8 + k], h2b[k], a);
            hf[o] = relu4(a);
        }
        vf4 lf = p[418];
        #pragma unroll
        for (int k = 0; k < 8; ++k) lf = fma4(p[402 + k], hf[k], lf);

        *(vf4*)&slog[0][rl][c] = lb;   // 16B-aligned LDS writes (c%4==0)
        *(vf4*)&slog[1][rl][c] = le;
        *(vf4*)&slog[2][rl][c] = lf;
    };

    // ---------------- Phase 1: two sequential passes ----------------
    do_quad(tid);                          // quads 0..255, all threads active
    __syncthreads();                       // register-pressure firewall
    if (tid < NQUAD - 256)                 // quads 256..417 (162 threads)
        do_quad(256 + tid);
    __syncthreads();

    // ------- Phase 2: x2 aligned_bilinear + sigmoid + NT vf4 stores -------
    // item = (h, rr, q): output rows y=2r+1 (A), y=2r+2 (B), cols 4q..4q+3.
    //   x=4q: (L[2q-1]+L[2q])/2   x=4q+1: L[2q]
    //   x=4q+2: (L[2q]+L[2q+1])/2 x=4q+3: L[2q+1]  (cols clamped to [0,151])
    // Row B averages LDS rows rr,rr+1 (halo pre-clamped). y=0==y=1 at r==0;
    // row B dropped at r==99.
    for (int it = tid; it < P2ITEMS; it += 256) {
        const int h   = it / (RSTRIP * 76);
        const int rem = it - h * (RSTRIP * 76);
        const int rr  = rem / 76;
        const int q   = rem - rr * 76;
        const int r   = r0 + rr;

        const int cm = max(2 * q - 1, 0);
        const int c0 = 2 * q;
        const int cp = min(2 * q + 1, WW - 1);

        const float Lm0 = slog[h][rr][cm],     L00 = slog[h][rr][c0],     Lp0 = slog[h][rr][cp];
        const float Lm1 = slog[h][rr + 1][cm], L01 = slog[h][rr + 1][c0], Lp1 = slog[h][rr + 1][cp];

        const float a0 = 0.5f * (Lm0 + L00);
        const float a1 = L00;
        const float a2 = 0.5f * (L00 + Lp0);
        const float a3 = Lp0;
        const float m  = 0.5f * (Lm0 + Lm1);
        const float z  = 0.5f * (L00 + L01);
        const float pz = 0.5f * (Lp0 + Lp1);
        const float b0 = 0.5f * (m + z);
        const float b1 = z;
        const float b2 = 0.5f * (z + pz);
        const float b3 = pz;

        vf4 A, B;
        A.x = 1.0f / (1.0f + __expf(-a0));
        A.y = 1.0f / (1.0f + __expf(-a1));
        A.z = 1.0f / (1.0f + __expf(-a2));
        A.w = 1.0f / (1.0f + __expf(-a3));
        B.x = 1.0f / (1.0f + __expf(-b0));
        B.y = 1.0f / (1.0f + __expf(-b1));
        B.z = 1.0f / (1.0f + __expf(-b2));
        B.w = 1.0f / (1.0f + __expf(-b3));

        float* __restrict__ O = out + ((size_t)h * n_inst + n) * OUT_PER_INST;
        const int xq = 4 * q;
        __builtin_nontemporal_store(A, (vf4*)(O + (size_t)(2 * r + 1) * OWID + xq)); // y=2r+1
        if (r == 0)
            __builtin_nontemporal_store(A, (vf4*)(O + xq));                           // y=0 (==y=1)
        if (r < HH - 1)
            __builtin_nontemporal_store(B, (vf4*)(O + (size_t)(2 * r + 2) * OWID + xq)); // y=2r+2
    }
}

extern "C" void kernel_launch(void* const* d_in, const int* in_sizes, int n_in,
                              void* d_out, int out_size, void* d_ws, size_t ws_size,
                              hipStream_t stream) {
    const float* fbody   = (const float*)d_in[0];
    const float* fedge   = (const float*)d_in[1];
    const float* params  = (const float*)d_in[2];
    const float* locs    = (const float*)d_in[3];
    const float* soi     = (const float*)d_in[4];
    const int*   im_inds = (const int*)d_in[5];
    const int*   fpn     = (const int*)d_in[6];
    // d_in[7] = mask_feat_stride (always 8; factor=2 baked into the closed form)

    const int n_inst = in_sizes[5];  // 128

    dim3 grid(NSTRIPS, n_inst);
    dmh_fused8_kernel<<<grid, dim3(256), 0, stream>>>(
        fbody, fedge, params, locs, soi, im_inds, fpn,
        (float*)d_out, n_inst);
}